// Round 11
// baseline (182.030 us; speedup 1.0000x reference)
//
#include <hip/hip_runtime.h>
#include <math.h>

#define LBL 26
#define MM  14
#define FF  128
#define HH  16
#define WW  8
#define KSZ 5
#define WPB 16              // words per block (fused fallback)
#define LPB (WPB * MM)      // 224
#define NITER 8

// ---------------- kernel 1: fold conv into emission weights ----------------
__global__ void prep_kernel(const float* __restrict__ K,
                            const float* __restrict__ b,
                            const float* __restrict__ W,
                            float* __restrict__ w2,
                            float* __restrict__ cvec) {
    int idx = blockIdx.x * blockDim.x + threadIdx.x;
    int stride = gridDim.x * blockDim.x;
    for (int o = idx; o < LBL * FF; o += stride) {
        int l = o / FF, f = o % FF;
        int qy = f / WW, qx = f % WW;
        double acc = 0.0;
        for (int ky = 0; ky < KSZ; ++ky) {
            int y = qy - ky + 2;
            if (y < 0 || y >= HH) continue;
            for (int kx = 0; kx < KSZ; ++kx) {
                int x = qx - kx + 2;
                if (x < 0 || x >= WW) continue;
                acc += (double)K[ky * KSZ + kx] * (double)W[l * FF + y * WW + x];
            }
        }
        w2[o] = (float)acc;
    }
    for (int l = idx; l < LBL; l += stride) {
        double s = 0.0;
        for (int f = 0; f < FF; ++f) s += (double)W[l * FF + f];
        cvec[l] = (float)(s * (double)b[0]);
    }
}

// ---------------- kernel A: emission scores (register-staged, LPT=2, word-major out) ----------------
// Thread = 2 letters (tid and tid+256 within block's 512). Halves weight-
// broadcast LDS reads per FMA vs LPT=1; doubles X-load MLP. Rotating register
// double-buffer, chunk loop NOT unrolled (r6 lesson). Repack in two phases
// through one 26.6KB slab (LDS total 40KB -> 4 blocks/CU).
template <int PAD>
__global__ __launch_bounds__(256) void scores_kernel(const float* __restrict__ X,
                                                     const float* __restrict__ w2,
                                                     const float* __restrict__ cvec,
                                                     float* __restrict__ sV) {
    __shared__ float4 wtile[32][LBL];      // [quad][label] : 13312 B
    __shared__ float  slds[256 * LBL];     // repack slab    : 26624 B

    const int tid  = threadIdx.x;
    const int letA = blockIdx.x * 512 + tid;         // first letter
    const int letB = letA + 256;                     // second letter

    const float4* W4 = (const float4*)w2;
    for (int i = tid; i < 32 * LBL; i += 256) {
        const int l = i >> 5, q = i & 31;
        wtile[q][l] = W4[i];
    }
    __syncthreads();

    const float4* xrA = (const float4*)X + (size_t)letA * 32;
    const float4* xrB = (const float4*)X + (size_t)letB * 32;

    float accA[LBL], accB[LBL];
#pragma unroll
    for (int l = 0; l < LBL; ++l) { accA[l] = cvec[l]; accB[l] = cvec[l]; }

#define COMPUTE(g, A0, A1, A2, A3, B0, B1, B2, B3)                         \
    {                                                                      \
        _Pragma("unroll")                                                  \
        for (int l = 0; l < LBL; ++l) {                                    \
            const float4 w0 = wtile[4 * (g) + 0][l];  /* broadcast */      \
            const float4 w1 = wtile[4 * (g) + 1][l];                       \
            const float4 w2v = wtile[4 * (g) + 2][l];                      \
            const float4 w3 = wtile[4 * (g) + 3][l];                       \
            float a = accA[l];                                             \
            a = fmaf(A0.x, w0.x, a); a = fmaf(A0.y, w0.y, a);              \
            a = fmaf(A0.z, w0.z, a); a = fmaf(A0.w, w0.w, a);              \
            a = fmaf(A1.x, w1.x, a); a = fmaf(A1.y, w1.y, a);              \
            a = fmaf(A1.z, w1.z, a); a = fmaf(A1.w, w1.w, a);              \
            a = fmaf(A2.x, w2v.x, a); a = fmaf(A2.y, w2v.y, a);            \
            a = fmaf(A2.z, w2v.z, a); a = fmaf(A2.w, w2v.w, a);            \
            a = fmaf(A3.x, w3.x, a); a = fmaf(A3.y, w3.y, a);              \
            a = fmaf(A3.z, w3.z, a); a = fmaf(A3.w, w3.w, a);              \
            accA[l] = a;                                                   \
            float bb = accB[l];                                            \
            bb = fmaf(B0.x, w0.x, bb); bb = fmaf(B0.y, w0.y, bb);          \
            bb = fmaf(B0.z, w0.z, bb); bb = fmaf(B0.w, w0.w, bb);          \
            bb = fmaf(B1.x, w1.x, bb); bb = fmaf(B1.y, w1.y, bb);          \
            bb = fmaf(B1.z, w1.z, bb); bb = fmaf(B1.w, w1.w, bb);          \
            bb = fmaf(B2.x, w2v.x, bb); bb = fmaf(B2.y, w2v.y, bb);        \
            bb = fmaf(B2.z, w2v.z, bb); bb = fmaf(B2.w, w2v.w, bb);        \
            bb = fmaf(B3.x, w3.x, bb); bb = fmaf(B3.y, w3.y, bb);          \
            bb = fmaf(B3.z, w3.z, bb); bb = fmaf(B3.w, w3.w, bb);          \
            accB[l] = bb;                                                  \
        }                                                                  \
    }

    float4 a0 = xrA[0], a1 = xrA[1], a2 = xrA[2], a3 = xrA[3];
    float4 b0 = xrB[0], b1 = xrB[1], b2 = xrB[2], b3 = xrB[3];
    for (int g = 0; g < 7; ++g) {      // NOT unrolled (r6 lesson)
        const float4 na0 = xrA[4 * g + 4], na1 = xrA[4 * g + 5];
        const float4 na2 = xrA[4 * g + 6], na3 = xrA[4 * g + 7];
        const float4 nb0 = xrB[4 * g + 4], nb1 = xrB[4 * g + 5];
        const float4 nb2 = xrB[4 * g + 6], nb3 = xrB[4 * g + 7];
        COMPUTE(g, a0, a1, a2, a3, b0, b1, b2, b3)
        a0 = na0; a1 = na1; a2 = na2; a3 = na3;
        b0 = nb0; b1 = nb1; b2 = nb2; b3 = nb3;
    }
    COMPUTE(7, a0, a1, a2, a3, b0, b1, b2, b3)
#undef COMPUTE

    // repack phase 1: letters [blk*512, +256)
#pragma unroll
    for (int l = 0; l < LBL; ++l) slds[tid * LBL + l] = accA[l];
    __syncthreads();
    {
        const size_t obase = (size_t)blockIdx.x * 512 * PAD;
        for (int idx = tid; idx < 256 * PAD; idx += 256) {
            const int ll = idx / PAD, lw = idx - ll * PAD;
            sV[obase + idx] = (lw < LBL) ? slds[ll * LBL + lw] : 0.0f;
        }
    }
    __syncthreads();
    // repack phase 2: letters [blk*512+256, +256)
#pragma unroll
    for (int l = 0; l < LBL; ++l) slds[tid * LBL + l] = accB[l];
    __syncthreads();
    {
        const size_t obase = ((size_t)blockIdx.x * 512 + 256) * PAD;
        for (int idx = tid; idx < 256 * PAD; idx += 256) {
            const int ll = idx / PAD, lw = idx - ll * PAD;
            sV[obase + idx] = (lw < LBL) ? slds[ll * LBL + lw] : 0.0f;
        }
    }
}

// ---------------- kernel B: Viterbi decode (j-per-lane, word-major scores) ----------------
// 32 lanes per word (j = label lane), 2 words/wave, 8 words per 256-block.
// Emission read per step = one coalesced 128B segment (word-major sV).
// vb row exchanged via wave-internal LDS (no barriers after T staging).
template <int PAD>
__global__ __launch_bounds__(256) void viterbi_kernel(const float* __restrict__ sV,
                                                      const float* __restrict__ Tm,
                                                      int* __restrict__ out) {
    __shared__ float T_lds[LBL * LBL];
    __shared__ float vb[8][32];

    const int tid  = threadIdx.x;
    for (int i = tid; i < LBL * LBL; i += 256) T_lds[i] = Tm[i];
    __syncthreads();

    const int wv   = tid >> 6;
    const int lane = tid & 63;
    const int half = lane >> 5;
    const int j    = lane & 31;
    const int jc   = (j < LBL) ? j : 25;         // clamped for safe reads

    const int wl   = wv * 2 + half;              // word slot in block
    const int word = blockIdx.x * 8 + wl;
    const float* sw = sV + (size_t)word * (MM * PAD);

    float tcol[LBL];                             // T[:, j]
#pragma unroll
    for (int i = 0; i < LBL; ++i) tcol[i] = T_lds[i * LBL + jc];

    float* vbw = &vb[wl][0];
    float v = (j < LBL) ? sw[j] : -INFINITY;
    vbw[j] = v;                                  // lanes 26..31 hold -inf (never read as i)
    unsigned bp_pack[4] = {0u, 0u, 0u, 0u};

#pragma unroll
    for (int t = 1; t < MM; ++t) {
        const float se = sw[t * PAD + jc];       // coalesced; issued early
        float best = -INFINITY;
        int bi = 0;
        const float4* q4 = (const float4*)vbw;   // broadcast reads (2 addrs/wave)
#define VCHK(vexpr, idx) { const float val = (vexpr) + tcol[idx]; \
                           if (val > best) { best = val; bi = idx; } }
        {
            float4 qq;
            qq = q4[0]; VCHK(qq.x, 0) VCHK(qq.y, 1) VCHK(qq.z, 2) VCHK(qq.w, 3)
            qq = q4[1]; VCHK(qq.x, 4) VCHK(qq.y, 5) VCHK(qq.z, 6) VCHK(qq.w, 7)
            qq = q4[2]; VCHK(qq.x, 8) VCHK(qq.y, 9) VCHK(qq.z, 10) VCHK(qq.w, 11)
            qq = q4[3]; VCHK(qq.x, 12) VCHK(qq.y, 13) VCHK(qq.z, 14) VCHK(qq.w, 15)
            qq = q4[4]; VCHK(qq.x, 16) VCHK(qq.y, 17) VCHK(qq.z, 18) VCHK(qq.w, 19)
            qq = q4[5]; VCHK(qq.x, 20) VCHK(qq.y, 21) VCHK(qq.z, 22) VCHK(qq.w, 23)
            qq = q4[6]; VCHK(qq.x, 24) VCHK(qq.y, 25)
        }
#undef VCHK
        v = (j < LBL) ? (best + se) : -INFINITY;
        vbw[j] = v;
        const int k = t - 1;
        bp_pack[k >> 2] |= (unsigned)bi << ((k & 3) * 8);
    }

    // argmax over j of final v (within 32-lane half), first occurrence
    float best = v;
    int bidx = (j < LBL) ? j : 999;
#pragma unroll
    for (int d = 1; d < 32; d <<= 1) {
        const float ov = __shfl_xor(best, d, 64);
        const int oi = __shfl_xor(bidx, d, 64);
        if (ov > best || (ov == best && oi < bidx)) { best = ov; bidx = oi; }
    }

    // backtrack (cur uniform within half; all lanes shuffle, lane j==0 stores)
    int cur = bidx;
    if (j == 0) out[word * MM + (MM - 1)] = cur;
#pragma unroll
    for (int k = MM - 2; k >= 0; --k) {
        const unsigned packed = __shfl(bp_pack[k >> 2], (lane & 32) | cur, 64);
        cur = (int)((packed >> ((k & 3) * 8)) & 0xffu);
        if (j == 0) out[word * MM + k] = cur;
    }
}

// ---------------- fallback: round-2 fused kernel (used if d_ws too small) ----------------
__global__ __launch_bounds__(256) void crf_kernel(const float* __restrict__ X,
                                                  const float* __restrict__ T,
                                                  const float* __restrict__ w2,
                                                  const float* __restrict__ cvec,
                                                  int* __restrict__ out) {
    __shared__ float4 tile[LPB * 4];
    __shared__ float  s_lds[WPB * MM * LBL];
    __shared__ float  v_lds[WPB * 32];

    const int tid = threadIdx.x;
    const int blk = blockIdx.x;
    const float4* X4 = (const float4*)X + (size_t)blk * LPB * (FF / 4);
    const float4* W4 = (const float4*)w2;

    float acc[LBL];
    if (tid < LPB) {
#pragma unroll
        for (int l = 0; l < LBL; ++l) acc[l] = cvec[l];
    }
    const int c0 = tid, c1 = tid + 256, c2 = tid + 512, c3 = tid + 768;
    float4 st0, st1, st2, st3;
    st0 = X4[(c0 >> 2) * 32 + (c0 & 3)];
    st1 = X4[(c1 >> 2) * 32 + (c1 & 3)];
    st2 = X4[(c2 >> 2) * 32 + (c2 & 3)];
    if (tid < 128) st3 = X4[(c3 >> 2) * 32 + (c3 & 3)];

    for (int iter = 0; iter < NITER; ++iter) {
        tile[(c0 >> 2) * 4 + ((c0 & 3) ^ ((c0 >> 2) & 3))] = st0;
        tile[(c1 >> 2) * 4 + ((c1 & 3) ^ ((c1 >> 2) & 3))] = st1;
        tile[(c2 >> 2) * 4 + ((c2 & 3) ^ ((c2 >> 2) & 3))] = st2;
        if (tid < 128) tile[(c3 >> 2) * 4 + ((c3 & 3) ^ ((c3 >> 2) & 3))] = st3;
        __syncthreads();
        if (iter + 1 < NITER) {
            const int ofs = (iter + 1) * 4;
            st0 = X4[(c0 >> 2) * 32 + ofs + (c0 & 3)];
            st1 = X4[(c1 >> 2) * 32 + ofs + (c1 & 3)];
            st2 = X4[(c2 >> 2) * 32 + ofs + (c2 & 3)];
            if (tid < 128) st3 = X4[(c3 >> 2) * 32 + ofs + (c3 & 3)];
        }
        if (tid < LPB) {
            const float4 xv0 = tile[tid * 4 + (0 ^ (tid & 3))];
            const float4 xv1 = tile[tid * 4 + (1 ^ (tid & 3))];
            const float4 xv2 = tile[tid * 4 + (2 ^ (tid & 3))];
            const float4 xv3 = tile[tid * 4 + (3 ^ (tid & 3))];
#pragma unroll
            for (int l = 0; l < LBL; ++l) {
                const float4 w0 = W4[l * 32 + iter * 4 + 0];
                const float4 w1 = W4[l * 32 + iter * 4 + 1];
                const float4 w2v = W4[l * 32 + iter * 4 + 2];
                const float4 w3 = W4[l * 32 + iter * 4 + 3];
                float a = acc[l];
                a = fmaf(xv0.x, w0.x, a); a = fmaf(xv0.y, w0.y, a);
                a = fmaf(xv0.z, w0.z, a); a = fmaf(xv0.w, w0.w, a);
                a = fmaf(xv1.x, w1.x, a); a = fmaf(xv1.y, w1.y, a);
                a = fmaf(xv1.z, w1.z, a); a = fmaf(xv1.w, w1.w, a);
                a = fmaf(xv2.x, w2v.x, a); a = fmaf(xv2.y, w2v.y, a);
                a = fmaf(xv2.z, w2v.z, a); a = fmaf(xv2.w, w2v.w, a);
                a = fmaf(xv3.x, w3.x, a); a = fmaf(xv3.y, w3.y, a);
                a = fmaf(xv3.z, w3.z, a); a = fmaf(xv3.w, w3.w, a);
                acc[l] = a;
            }
        }
        __syncthreads();
    }
    if (tid < LPB) {
#pragma unroll
        for (int l = 0; l < LBL; ++l) s_lds[tid * LBL + l] = acc[l];
    }
    __syncthreads();

    const int lane = tid & 63;
    const int wvid = tid >> 6;
    const int half = lane >> 5;
    const int j = lane & 31;
    const int jc = (j < LBL) ? j : 0;

    float tcol[LBL];
#pragma unroll
    for (int i = 0; i < LBL; ++i) tcol[i] = T[i * LBL + jc];

    for (int pass = 0; pass < 2; ++pass) {
        const int wi = pass * 8 + wvid * 2 + half;
        const int word = blk * WPB + wi;
        const float* sw = s_lds + wi * MM * LBL;
        float* vbp = v_lds + wi * 32;

        float v = (j < LBL) ? sw[j] : -INFINITY;
        if (j < LBL) vbp[j] = v;
        unsigned bp_pack[4] = {0u, 0u, 0u, 0u};

#pragma unroll
        for (int t = 1; t < MM; ++t) {
            float best = -INFINITY;
            int bi = 0;
#define VCHK(vexpr, idx) { const float val = (vexpr) + tcol[idx]; \
                           if (val > best) { best = val; bi = idx; } }
            {
                float4 vv;
                vv = *(const float4*)(vbp + 0);
                VCHK(vv.x, 0) VCHK(vv.y, 1) VCHK(vv.z, 2) VCHK(vv.w, 3)
                vv = *(const float4*)(vbp + 4);
                VCHK(vv.x, 4) VCHK(vv.y, 5) VCHK(vv.z, 6) VCHK(vv.w, 7)
                vv = *(const float4*)(vbp + 8);
                VCHK(vv.x, 8) VCHK(vv.y, 9) VCHK(vv.z, 10) VCHK(vv.w, 11)
                vv = *(const float4*)(vbp + 12);
                VCHK(vv.x, 12) VCHK(vv.y, 13) VCHK(vv.z, 14) VCHK(vv.w, 15)
                vv = *(const float4*)(vbp + 16);
                VCHK(vv.x, 16) VCHK(vv.y, 17) VCHK(vv.z, 18) VCHK(vv.w, 19)
                vv = *(const float4*)(vbp + 20);
                VCHK(vv.x, 20) VCHK(vv.y, 21) VCHK(vv.z, 22) VCHK(vv.w, 23)
                vv = *(const float4*)(vbp + 24);
                VCHK(vv.x, 24) VCHK(vv.y, 25)
            }
#undef VCHK
            v = (j < LBL) ? (best + sw[t * LBL + j]) : -INFINITY;
            if (j < LBL) vbp[j] = v;
            const int k = t - 1;
            bp_pack[k >> 2] |= (unsigned)bi << ((k & 3) * 8);
        }

        float best = v;
        int bidx = (j < LBL) ? j : 999;
#pragma unroll
        for (int d = 1; d < 32; d <<= 1) {
            const float ov = __shfl_xor(best, d, 64);
            const int oi = __shfl_xor(bidx, d, 64);
            if (ov > best || (ov == best && oi < bidx)) { best = ov; bidx = oi; }
        }
        int cur = bidx;
        if (j == 0) out[word * MM + (MM - 1)] = cur;
#pragma unroll
        for (int k = MM - 2; k >= 0; --k) {
            const unsigned packed = __shfl(bp_pack[k >> 2], (lane & 32) | cur, 64);
            cur = (int)((packed >> ((k & 3) * 8)) & 0xffu);
            if (j == 0) out[word * MM + k] = cur;
        }
        __syncthreads();
    }
}

extern "C" void kernel_launch(void* const* d_in, const int* in_sizes, int n_in,
                              void* d_out, int out_size, void* d_ws, size_t ws_size,
                              hipStream_t stream) {
    const float* X = (const float*)d_in[0];
    const float* K = (const float*)d_in[1];
    const float* b = (const float*)d_in[2];
    const float* W = (const float*)d_in[3];
    const float* T = (const float*)d_in[4];
    int* out = (int*)d_out;

    const int nw = in_sizes[0] / (MM * FF);     // 32768 words
    const int NLET = nw * MM;                   // 458752 letters

    const size_t w_bytes = (size_t)(LBL * FF + LBL) * sizeof(float);
    const size_t sV28    = (size_t)NLET * 28 * sizeof(float);   // ~51.4 MB
    const size_t sV26    = (size_t)NLET * 26 * sizeof(float);   // ~47.7 MB

    const bool shape_ok = (NLET % 512) == 0 && (nw % 8) == 0;

    if (shape_ok && ws_size >= sV28 + w_bytes) {
        float* sV   = (float*)d_ws;
        float* w2   = (float*)((char*)d_ws + sV28);
        float* cvec = w2 + LBL * FF;
        prep_kernel<<<(LBL * FF + 255) / 256, 256, 0, stream>>>(K, b, W, w2, cvec);
        scores_kernel<28><<<NLET / 512, 256, 0, stream>>>(X, w2, cvec, sV);
        viterbi_kernel<28><<<nw / 8, 256, 0, stream>>>(sV, T, out);
    } else if (shape_ok && ws_size >= sV26 + w_bytes) {
        float* sV   = (float*)d_ws;
        float* w2   = (float*)((char*)d_ws + sV26);
        float* cvec = w2 + LBL * FF;
        prep_kernel<<<(LBL * FF + 255) / 256, 256, 0, stream>>>(K, b, W, w2, cvec);
        scores_kernel<26><<<NLET / 512, 256, 0, stream>>>(X, w2, cvec, sV);
        viterbi_kernel<26><<<nw / 8, 256, 0, stream>>>(sV, T, out);
    } else {
        float* w2   = (float*)d_ws;
        float* cvec = w2 + LBL * FF;
        prep_kernel<<<(LBL * FF + 255) / 256, 256, 0, stream>>>(K, b, W, w2, cvec);
        crf_kernel<<<nw / WPB, 256, 0, stream>>>(X, T, w2, cvec, out);
    }
}

// Round 12
// 144.658 us; speedup vs baseline: 1.2583x; 1.2583x over previous
//
#include <hip/hip_runtime.h>
#include <math.h>

#define LBL 26
#define MM  14
#define FF  128
#define HH  16
#define WW  8
#define KSZ 5
#define WPB 16              // words per block (fused fallback)
#define LPB (WPB * MM)      // 224
#define NITER 8

// ---------------- kernel 1: fold conv into emission weights ----------------
__global__ void prep_kernel(const float* __restrict__ K,
                            const float* __restrict__ b,
                            const float* __restrict__ W,
                            float* __restrict__ w2,
                            float* __restrict__ cvec) {
    int idx = blockIdx.x * blockDim.x + threadIdx.x;
    int stride = gridDim.x * blockDim.x;
    for (int o = idx; o < LBL * FF; o += stride) {
        int l = o / FF, f = o % FF;
        int qy = f / WW, qx = f % WW;
        double acc = 0.0;
        for (int ky = 0; ky < KSZ; ++ky) {
            int y = qy - ky + 2;
            if (y < 0 || y >= HH) continue;
            for (int kx = 0; kx < KSZ; ++kx) {
                int x = qx - kx + 2;
                if (x < 0 || x >= WW) continue;
                acc += (double)K[ky * KSZ + kx] * (double)W[l * FF + y * WW + x];
            }
        }
        w2[o] = (float)acc;
    }
    for (int l = idx; l < LBL; l += stride) {
        double s = 0.0;
        for (int f = 0; f < FF; ++f) s += (double)W[l * FF + f];
        cvec[l] = (float)(s * (double)b[0]);
    }
}

// ---------------- kernel A: emission scores (register-staged, LPT=1, word-major out) ----------------
// r10 proven config. Thread = one letter, X row as 8 back-to-back float4
// groups (line-complete), weights via LDS broadcast, rotating register
// double-buffer, chunk loop NOT unrolled (r6 lesson; r11 lesson: LPT=2's
// 52-acc register load kills occupancy — keep LPT=1).
template <int PAD>
__global__ __launch_bounds__(256) void scores_kernel(const float* __restrict__ X,
                                                     const float* __restrict__ w2,
                                                     const float* __restrict__ cvec,
                                                     float* __restrict__ sV) {
    __shared__ float4 wtile[32][LBL];      // [quad][label] : 13312 B
    __shared__ float  slds[256 * LBL];     // repack slab    : 26624 B

    const int tid    = threadIdx.x;
    const int letter = blockIdx.x * 256 + tid;

    const float4* W4 = (const float4*)w2;
    for (int i = tid; i < 32 * LBL; i += 256) {
        const int l = i >> 5, q = i & 31;
        wtile[q][l] = W4[i];
    }
    __syncthreads();

    const float4* xr = (const float4*)X + (size_t)letter * 32;

    float acc[LBL];
#pragma unroll
    for (int l = 0; l < LBL; ++l) acc[l] = cvec[l];   // uniform -> s_load

#define COMPUTE(g, C0, C1, C2, C3)                                         \
    {                                                                      \
        _Pragma("unroll")                                                  \
        for (int l = 0; l < LBL; ++l) {                                    \
            const float4 w0 = wtile[4 * (g) + 0][l];  /* broadcast */      \
            const float4 w1 = wtile[4 * (g) + 1][l];                       \
            const float4 w2v = wtile[4 * (g) + 2][l];                      \
            const float4 w3 = wtile[4 * (g) + 3][l];                       \
            float a = acc[l];                                              \
            a = fmaf(C0.x, w0.x, a); a = fmaf(C0.y, w0.y, a);              \
            a = fmaf(C0.z, w0.z, a); a = fmaf(C0.w, w0.w, a);              \
            a = fmaf(C1.x, w1.x, a); a = fmaf(C1.y, w1.y, a);              \
            a = fmaf(C1.z, w1.z, a); a = fmaf(C1.w, w1.w, a);              \
            a = fmaf(C2.x, w2v.x, a); a = fmaf(C2.y, w2v.y, a);            \
            a = fmaf(C2.z, w2v.z, a); a = fmaf(C2.w, w2v.w, a);            \
            a = fmaf(C3.x, w3.x, a); a = fmaf(C3.y, w3.y, a);              \
            a = fmaf(C3.z, w3.z, a); a = fmaf(C3.w, w3.w, a);              \
            acc[l] = a;                                                    \
        }                                                                  \
    }

    float4 c0 = xr[0], c1 = xr[1], c2 = xr[2], c3 = xr[3];
    for (int g = 0; g < 7; ++g) {      // NOT unrolled (r6 lesson)
        const float4 n0 = xr[4 * g + 4], n1 = xr[4 * g + 5];
        const float4 n2 = xr[4 * g + 6], n3 = xr[4 * g + 7];
        COMPUTE(g, c0, c1, c2, c3)
        c0 = n0; c1 = n1; c2 = n2; c3 = n3;
    }
    COMPUTE(7, c0, c1, c2, c3)
#undef COMPUTE

    // repack: LDS slab then coalesced word-major write (letter*PAD + l)
#pragma unroll
    for (int l = 0; l < LBL; ++l) slds[tid * LBL + l] = acc[l];
    __syncthreads();
    const size_t obase = (size_t)blockIdx.x * 256 * PAD;
    for (int idx = tid; idx < 256 * PAD; idx += 256) {
        const int ll = idx / PAD, lw = idx - ll * PAD;
        sV[obase + idx] = (lw < LBL) ? slds[ll * LBL + lw] : 0.0f;
    }
}

// ---------------- kernel B: Viterbi decode (j-per-lane, word-major scores) ----------------
// r10 proven config. 32 lanes per word (j = label lane), 2 words/wave,
// 8 words per 256-block. Emission read per step = one coalesced 128B segment.
// vb row exchanged via wave-internal LDS (no barriers after T staging).
template <int PAD>
__global__ __launch_bounds__(256) void viterbi_kernel(const float* __restrict__ sV,
                                                      const float* __restrict__ Tm,
                                                      int* __restrict__ out) {
    __shared__ float T_lds[LBL * LBL];
    __shared__ float vb[8][32];

    const int tid  = threadIdx.x;
    for (int i = tid; i < LBL * LBL; i += 256) T_lds[i] = Tm[i];
    __syncthreads();

    const int wv   = tid >> 6;
    const int lane = tid & 63;
    const int half = lane >> 5;
    const int j    = lane & 31;
    const int jc   = (j < LBL) ? j : 25;         // clamped for safe reads

    const int wl   = wv * 2 + half;              // word slot in block
    const int word = blockIdx.x * 8 + wl;
    const float* sw = sV + (size_t)word * (MM * PAD);

    float tcol[LBL];                             // T[:, j]
#pragma unroll
    for (int i = 0; i < LBL; ++i) tcol[i] = T_lds[i * LBL + jc];

    float* vbw = &vb[wl][0];
    float v = (j < LBL) ? sw[j] : -INFINITY;
    vbw[j] = v;                                  // lanes 26..31 hold -inf (never read as i)
    unsigned bp_pack[4] = {0u, 0u, 0u, 0u};

#pragma unroll
    for (int t = 1; t < MM; ++t) {
        const float se = sw[t * PAD + jc];       // coalesced; issued early
        float best = -INFINITY;
        int bi = 0;
        const float4* q4 = (const float4*)vbw;   // broadcast reads (2 addrs/wave)
#define VCHK(vexpr, idx) { const float val = (vexpr) + tcol[idx]; \
                           if (val > best) { best = val; bi = idx; } }
        {
            float4 qq;
            qq = q4[0]; VCHK(qq.x, 0) VCHK(qq.y, 1) VCHK(qq.z, 2) VCHK(qq.w, 3)
            qq = q4[1]; VCHK(qq.x, 4) VCHK(qq.y, 5) VCHK(qq.z, 6) VCHK(qq.w, 7)
            qq = q4[2]; VCHK(qq.x, 8) VCHK(qq.y, 9) VCHK(qq.z, 10) VCHK(qq.w, 11)
            qq = q4[3]; VCHK(qq.x, 12) VCHK(qq.y, 13) VCHK(qq.z, 14) VCHK(qq.w, 15)
            qq = q4[4]; VCHK(qq.x, 16) VCHK(qq.y, 17) VCHK(qq.z, 18) VCHK(qq.w, 19)
            qq = q4[5]; VCHK(qq.x, 20) VCHK(qq.y, 21) VCHK(qq.z, 22) VCHK(qq.w, 23)
            qq = q4[6]; VCHK(qq.x, 24) VCHK(qq.y, 25)
        }
#undef VCHK
        v = (j < LBL) ? (best + se) : -INFINITY;
        vbw[j] = v;
        const int k = t - 1;
        bp_pack[k >> 2] |= (unsigned)bi << ((k & 3) * 8);
    }

    // argmax over j of final v (within 32-lane half), first occurrence
    float best = v;
    int bidx = (j < LBL) ? j : 999;
#pragma unroll
    for (int d = 1; d < 32; d <<= 1) {
        const float ov = __shfl_xor(best, d, 64);
        const int oi = __shfl_xor(bidx, d, 64);
        if (ov > best || (ov == best && oi < bidx)) { best = ov; bidx = oi; }
    }

    // backtrack (cur uniform within half; all lanes shuffle, lane j==0 stores)
    int cur = bidx;
    if (j == 0) out[word * MM + (MM - 1)] = cur;
#pragma unroll
    for (int k = MM - 2; k >= 0; --k) {
        const unsigned packed = __shfl(bp_pack[k >> 2], (lane & 32) | cur, 64);
        cur = (int)((packed >> ((k & 3) * 8)) & 0xffu);
        if (j == 0) out[word * MM + k] = cur;
    }
}

// ---------------- fallback: round-2 fused kernel (used if d_ws too small) ----------------
__global__ __launch_bounds__(256) void crf_kernel(const float* __restrict__ X,
                                                  const float* __restrict__ T,
                                                  const float* __restrict__ w2,
                                                  const float* __restrict__ cvec,
                                                  int* __restrict__ out) {
    __shared__ float4 tile[LPB * 4];
    __shared__ float  s_lds[WPB * MM * LBL];
    __shared__ float  v_lds[WPB * 32];

    const int tid = threadIdx.x;
    const int blk = blockIdx.x;
    const float4* X4 = (const float4*)X + (size_t)blk * LPB * (FF / 4);
    const float4* W4 = (const float4*)w2;

    float acc[LBL];
    if (tid < LPB) {
#pragma unroll
        for (int l = 0; l < LBL; ++l) acc[l] = cvec[l];
    }
    const int c0 = tid, c1 = tid + 256, c2 = tid + 512, c3 = tid + 768;
    float4 st0, st1, st2, st3;
    st0 = X4[(c0 >> 2) * 32 + (c0 & 3)];
    st1 = X4[(c1 >> 2) * 32 + (c1 & 3)];
    st2 = X4[(c2 >> 2) * 32 + (c2 & 3)];
    if (tid < 128) st3 = X4[(c3 >> 2) * 32 + (c3 & 3)];

    for (int iter = 0; iter < NITER; ++iter) {
        tile[(c0 >> 2) * 4 + ((c0 & 3) ^ ((c0 >> 2) & 3))] = st0;
        tile[(c1 >> 2) * 4 + ((c1 & 3) ^ ((c1 >> 2) & 3))] = st1;
        tile[(c2 >> 2) * 4 + ((c2 & 3) ^ ((c2 >> 2) & 3))] = st2;
        if (tid < 128) tile[(c3 >> 2) * 4 + ((c3 & 3) ^ ((c3 >> 2) & 3))] = st3;
        __syncthreads();
        if (iter + 1 < NITER) {
            const int ofs = (iter + 1) * 4;
            st0 = X4[(c0 >> 2) * 32 + ofs + (c0 & 3)];
            st1 = X4[(c1 >> 2) * 32 + ofs + (c1 & 3)];
            st2 = X4[(c2 >> 2) * 32 + ofs + (c2 & 3)];
            if (tid < 128) st3 = X4[(c3 >> 2) * 32 + ofs + (c3 & 3)];
        }
        if (tid < LPB) {
            const float4 xv0 = tile[tid * 4 + (0 ^ (tid & 3))];
            const float4 xv1 = tile[tid * 4 + (1 ^ (tid & 3))];
            const float4 xv2 = tile[tid * 4 + (2 ^ (tid & 3))];
            const float4 xv3 = tile[tid * 4 + (3 ^ (tid & 3))];
#pragma unroll
            for (int l = 0; l < LBL; ++l) {
                const float4 w0 = W4[l * 32 + iter * 4 + 0];
                const float4 w1 = W4[l * 32 + iter * 4 + 1];
                const float4 w2v = W4[l * 32 + iter * 4 + 2];
                const float4 w3 = W4[l * 32 + iter * 4 + 3];
                float a = acc[l];
                a = fmaf(xv0.x, w0.x, a); a = fmaf(xv0.y, w0.y, a);
                a = fmaf(xv0.z, w0.z, a); a = fmaf(xv0.w, w0.w, a);
                a = fmaf(xv1.x, w1.x, a); a = fmaf(xv1.y, w1.y, a);
                a = fmaf(xv1.z, w1.z, a); a = fmaf(xv1.w, w1.w, a);
                a = fmaf(xv2.x, w2v.x, a); a = fmaf(xv2.y, w2v.y, a);
                a = fmaf(xv2.z, w2v.z, a); a = fmaf(xv2.w, w2v.w, a);
                a = fmaf(xv3.x, w3.x, a); a = fmaf(xv3.y, w3.y, a);
                a = fmaf(xv3.z, w3.z, a); a = fmaf(xv3.w, w3.w, a);
                acc[l] = a;
            }
        }
        __syncthreads();
    }
    if (tid < LPB) {
#pragma unroll
        for (int l = 0; l < LBL; ++l) s_lds[tid * LBL + l] = acc[l];
    }
    __syncthreads();

    const int lane = tid & 63;
    const int wvid = tid >> 6;
    const int half = lane >> 5;
    const int j = lane & 31;
    const int jc = (j < LBL) ? j : 0;

    float tcol[LBL];
#pragma unroll
    for (int i = 0; i < LBL; ++i) tcol[i] = T[i * LBL + jc];

    for (int pass = 0; pass < 2; ++pass) {
        const int wi = pass * 8 + wvid * 2 + half;
        const int word = blk * WPB + wi;
        const float* sw = s_lds + wi * MM * LBL;
        float* vbp = v_lds + wi * 32;

        float v = (j < LBL) ? sw[j] : -INFINITY;
        if (j < LBL) vbp[j] = v;
        unsigned bp_pack[4] = {0u, 0u, 0u, 0u};

#pragma unroll
        for (int t = 1; t < MM; ++t) {
            float best = -INFINITY;
            int bi = 0;
#define VCHK(vexpr, idx) { const float val = (vexpr) + tcol[idx]; \
                           if (val > best) { best = val; bi = idx; } }
            {
                float4 vv;
                vv = *(const float4*)(vbp + 0);
                VCHK(vv.x, 0) VCHK(vv.y, 1) VCHK(vv.z, 2) VCHK(vv.w, 3)
                vv = *(const float4*)(vbp + 4);
                VCHK(vv.x, 4) VCHK(vv.y, 5) VCHK(vv.z, 6) VCHK(vv.w, 7)
                vv = *(const float4*)(vbp + 8);
                VCHK(vv.x, 8) VCHK(vv.y, 9) VCHK(vv.z, 10) VCHK(vv.w, 11)
                vv = *(const float4*)(vbp + 12);
                VCHK(vv.x, 12) VCHK(vv.y, 13) VCHK(vv.z, 14) VCHK(vv.w, 15)
                vv = *(const float4*)(vbp + 16);
                VCHK(vv.x, 16) VCHK(vv.y, 17) VCHK(vv.z, 18) VCHK(vv.w, 19)
                vv = *(const float4*)(vbp + 20);
                VCHK(vv.x, 20) VCHK(vv.y, 21) VCHK(vv.z, 22) VCHK(vv.w, 23)
                vv = *(const float4*)(vbp + 24);
                VCHK(vv.x, 24) VCHK(vv.y, 25)
            }
#undef VCHK
            v = (j < LBL) ? (best + sw[t * LBL + j]) : -INFINITY;
            if (j < LBL) vbp[j] = v;
            const int k = t - 1;
            bp_pack[k >> 2] |= (unsigned)bi << ((k & 3) * 8);
        }

        float best = v;
        int bidx = (j < LBL) ? j : 999;
#pragma unroll
        for (int d = 1; d < 32; d <<= 1) {
            const float ov = __shfl_xor(best, d, 64);
            const int oi = __shfl_xor(bidx, d, 64);
            if (ov > best || (ov == best && oi < bidx)) { best = ov; bidx = oi; }
        }
        int cur = bidx;
        if (j == 0) out[word * MM + (MM - 1)] = cur;
#pragma unroll
        for (int k = MM - 2; k >= 0; --k) {
            const unsigned packed = __shfl(bp_pack[k >> 2], (lane & 32) | cur, 64);
            cur = (int)((packed >> ((k & 3) * 8)) & 0xffu);
            if (j == 0) out[word * MM + k] = cur;
        }
        __syncthreads();
    }
}

extern "C" void kernel_launch(void* const* d_in, const int* in_sizes, int n_in,
                              void* d_out, int out_size, void* d_ws, size_t ws_size,
                              hipStream_t stream) {
    const float* X = (const float*)d_in[0];
    const float* K = (const float*)d_in[1];
    const float* b = (const float*)d_in[2];
    const float* W = (const float*)d_in[3];
    const float* T = (const float*)d_in[4];
    int* out = (int*)d_out;

    const int nw = in_sizes[0] / (MM * FF);     // 32768 words
    const int NLET = nw * MM;                   // 458752 letters

    const size_t w_bytes = (size_t)(LBL * FF + LBL) * sizeof(float);
    const size_t sV28    = (size_t)NLET * 28 * sizeof(float);   // ~51.4 MB
    const size_t sV26    = (size_t)NLET * 26 * sizeof(float);   // ~47.7 MB

    const bool shape_ok = (NLET % 256) == 0 && (nw % 8) == 0;

    if (shape_ok && ws_size >= sV28 + w_bytes) {
        float* sV   = (float*)d_ws;
        float* w2   = (float*)((char*)d_ws + sV28);
        float* cvec = w2 + LBL * FF;
        prep_kernel<<<(LBL * FF + 255) / 256, 256, 0, stream>>>(K, b, W, w2, cvec);
        scores_kernel<28><<<NLET / 256, 256, 0, stream>>>(X, w2, cvec, sV);
        viterbi_kernel<28><<<nw / 8, 256, 0, stream>>>(sV, T, out);
    } else if (shape_ok && ws_size >= sV26 + w_bytes) {
        float* sV   = (float*)d_ws;
        float* w2   = (float*)((char*)d_ws + sV26);
        float* cvec = w2 + LBL * FF;
        prep_kernel<<<(LBL * FF + 255) / 256, 256, 0, stream>>>(K, b, W, w2, cvec);
        scores_kernel<26><<<NLET / 256, 256, 0, stream>>>(X, w2, cvec, sV);
        viterbi_kernel<26><<<nw / 8, 256, 0, stream>>>(sV, T, out);
    } else {
        float* w2   = (float*)d_ws;
        float* cvec = w2 + LBL * FF;
        prep_kernel<<<(LBL * FF + 255) / 256, 256, 0, stream>>>(K, b, W, w2, cvec);
        crf_kernel<<<nw / WPB, 256, 0, stream>>>(X, T, w2, cvec, out);
    }
}